// Round 6
// baseline (145.998 us; speedup 1.0000x reference)
//
#include <hip/hip_runtime.h>

// LlamaAttention — Round 13: r12 barrier-free GEMM + 2 blocks/CU overlap.
//
// out = x @ (Wo @ Wv)^T  (softmax == I, established r0-r12).
// r12 post-mortem: 42.4 us, occupancy 15.6% (96KB LDS -> 1 block/CU).
// Serial per-block phases (x-stage ~8us, K-loop, epilogue ~8us) cannot
// overlap across blocks at 1 block/CU. This round: 32-row stripes,
// 512 blocks x 512 thr (8 waves x 32rows x 96cols, disjoint cols -> W
// read once/block), LDS 48KB -> 2 blocks/CU, 4 waves/SIMD; bursts of
// one block overlap the K-loop of the other. VGPR budget 128 (incl
// 48 AGPR acc) via __launch_bounds__(512,4). wt layout, swizzle, dbuf
// schedule, prep_w (bit-identical W) unchanged from r12.

typedef unsigned short u16;
typedef __attribute__((ext_vector_type(8))) short short8;      // 16 B
typedef __attribute__((ext_vector_type(8))) _Float16 f16x8;    // 4 VGPR MFMA frag
typedef __attribute__((ext_vector_type(4))) float float4v;

__device__ inline u16 f16b(float f) {
  union { _Float16 h; u16 u; } v; v.h = (_Float16)f; return v.u;  // v_cvt_f16_f32 RNE
}

__device__ inline u16 f32_to_bf16(float f) {        // fallback path only
  union { float f; unsigned int u; } v; v.f = f;
  unsigned int r = v.u + 0x7FFF + ((v.u >> 16) & 1);
  return (u16)(r >> 16);
}

// ---------------- prep: W = Wo @ Wv, fp32 accum, f16 tiled ----------------
// wt layout for direct B-frag loads: element (o, h) at
//   wt[(h>>5)*24576 + o*32 + ((h>>3)&3)*8 + (h&7)]
// (wave frag load = 1 KB contiguous). Bit-identical W vs r10-r12.
__global__ __launch_bounds__(256)
void prep_w(const float* __restrict__ Wv, const float* __restrict__ Wo,
            u16* __restrict__ wt) {
  __shared__ __align__(16) float wo[4][256];            // 4 KB
  const int og = blockIdx.x / 3, hc = blockIdx.x % 3;   // 192 o-grp x 3 h-chunk
  const int o0 = og * 4;
  ((float4v*)&wo[0][0])[threadIdx.x] =
      ((const float4v*)(Wo + (size_t)o0 * 256))[threadIdx.x];
  __syncthreads();
  const int h = hc * 256 + threadIdx.x;
  float acc[4] = {0.f, 0.f, 0.f, 0.f};
  float wvA[8], wvB[8];
#pragma unroll
  for (int u = 0; u < 8; ++u) wvA[u] = Wv[(size_t)u * 768 + h];

#define PFMA(wv_, kk_)                                                       \
  _Pragma("unroll")                                                          \
  for (int j = 0; j < 4; ++j) {                                              \
    float4v c0 = *(const float4v*)(&wo[j][kk_]);                             \
    float4v c1 = *(const float4v*)(&wo[j][(kk_) + 4]);                       \
    acc[j] = fmaf(c0[0], wv_[0], acc[j]);                                    \
    acc[j] = fmaf(c0[1], wv_[1], acc[j]);                                    \
    acc[j] = fmaf(c0[2], wv_[2], acc[j]);                                    \
    acc[j] = fmaf(c0[3], wv_[3], acc[j]);                                    \
    acc[j] = fmaf(c1[0], wv_[4], acc[j]);                                    \
    acc[j] = fmaf(c1[1], wv_[5], acc[j]);                                    \
    acc[j] = fmaf(c1[2], wv_[6], acc[j]);                                    \
    acc[j] = fmaf(c1[3], wv_[7], acc[j]);                                    \
  }

  for (int k = 0; k < 240; k += 16) {
#pragma unroll
    for (int u = 0; u < 8; ++u) wvB[u] = Wv[(size_t)(k + 8 + u) * 768 + h];
    PFMA(wvA, k)
#pragma unroll
    for (int u = 0; u < 8; ++u) wvA[u] = Wv[(size_t)(k + 16 + u) * 768 + h];
    PFMA(wvB, k + 8)
  }
#pragma unroll
  for (int u = 0; u < 8; ++u) wvB[u] = Wv[(size_t)(248 + u) * 768 + h];
  PFMA(wvA, 240)
  PFMA(wvB, 248)
#undef PFMA

  const int kt = h >> 5, qq = (h >> 3) & 3, e = h & 7;
#pragma unroll
  for (int j = 0; j < 4; ++j)
    wt[(size_t)kt * 24576 + (o0 + j) * 32 + qq * 8 + e] = f16b(acc[j]);
}

// ---------------- main: out[16384,768] = x @ W^T, zero-barrier loop -------
// Block: 512 thr / 8 waves; 32 rows x 768 cols; wave w owns cols w*96..+95
// (disjoint -> W read once per block). LDS: x stripe f16 [32][96 chunks],
// chunk stored at c^(row&7).
__global__ __launch_bounds__(512, 4)   // 4 waves/SIMD -> total regs <= 128
void gemm_xw(const float* __restrict__ x, const u16* __restrict__ wt,
             float* __restrict__ out) {
  __shared__ __align__(16) u16 S[32 * 768];       // 48 KB -> 2 blocks/CU

  const int tid = threadIdx.x;
  const int w = tid >> 6, l = tid & 63;
  const int q = l >> 4, mr = l & 15;
  const int row0 = blockIdx.x * 32;

  // ---- stage x[32][768] fp32 -> LDS f16, chunk-swizzled, ONCE ----
  {
    const int sr = tid >> 4, m = tid & 15;        // row 0..31, 16 thr/row
    const float* gr = x + (size_t)(row0 + sr) * 768;
    u16* lr = S + sr * 768;
    const int key = sr & 7;
#pragma unroll
    for (int j = 0; j < 6; ++j) {
      const int c = m + 16 * j;                   // chunk 0..95
      float4v v0 = *(const float4v*)(gr + c * 8);
      float4v v1 = *(const float4v*)(gr + c * 8 + 4);
      union { u16 h[8]; short8 s; } p;
#pragma unroll
      for (int e = 0; e < 4; ++e) { p.h[e] = f16b(v0[e]); p.h[e + 4] = f16b(v1[e]); }
      *(short8*)(lr + ((c ^ key) << 3)) = p.s;
    }
  }
  __syncthreads();                                // the ONLY barrier

  // B-frag lane base: wt + col*32 + q*8, col = w*96 + jn*16 + mr
  const u16* wl = wt + (w * 96 + mr) * 32 + q * 8;
  const int akey = mr & 7;

  float4v acc[2][6];
#pragma unroll
  for (int i = 0; i < 2; ++i)
#pragma unroll
    for (int j = 0; j < 6; ++j) acc[i][j] = (float4v){0.f, 0.f, 0.f, 0.f};

  f16x8 a0[2], a1[2], b0[6], b1[6];

#define LDA(av_, kt_)                                                        \
  _Pragma("unroll")                                                          \
  for (int im = 0; im < 2; ++im)                                             \
    av_[im] = *(const f16x8*)(                                               \
        &S[(im * 16 + mr) * 768 + ((((kt_) * 4 + q) ^ akey) << 3)]);

#define LDB(bv_, kt_)                                                        \
  { const u16* gp = wl + (size_t)(kt_) * 24576;                              \
    _Pragma("unroll")                                                        \
    for (int jn = 0; jn < 6; ++jn)                                           \
      bv_[jn] = *(const f16x8*)(gp + jn * 512); }

#define MM(av_, bv_)                                                         \
  { __builtin_amdgcn_s_setprio(1);                                           \
    _Pragma("unroll")                                                        \
    for (int im = 0; im < 2; ++im)                                           \
      _Pragma("unroll")                                                      \
      for (int jn = 0; jn < 6; ++jn)                                         \
        acc[im][jn] = __builtin_amdgcn_mfma_f32_16x16x32_f16(                \
            av_[im], bv_[jn], acc[im][jn], 0, 0, 0);                         \
    __builtin_amdgcn_s_setprio(0); }

  LDB(b0, 0)
  LDA(a0, 0)
  for (int kt = 0; kt < 22; kt += 2) {
    LDB(b1, kt + 1)
    LDA(a1, kt + 1)
    MM(a0, b0)
    LDB(b0, kt + 2)
    LDA(a0, kt + 2)
    MM(a1, b1)
  }
  LDB(b1, 23)
  LDA(a1, 23)
  MM(a0, b0)
  MM(a1, b1)

#undef LDA
#undef LDB
#undef MM

  // ---- epilogue: C/D col=lane&15, row=q*4+reg (m89-verified) ----
#pragma unroll
  for (int im = 0; im < 2; ++im)
#pragma unroll
    for (int jn = 0; jn < 6; ++jn) {
      const int r0 = row0 + im * 16 + q * 4;
      const int c  = w * 96 + jn * 16 + mr;
#pragma unroll
      for (int r = 0; r < 4; ++r)
        out[(size_t)(r0 + r) * 768 + c] = acc[im][jn][r];
    }
}

// ---------------- fallback (no workspace): verified r7 kernel ----------------
__global__ __launch_bounds__(512, 1)
void fused_fallback(const float* __restrict__ x,
                    const float* __restrict__ Wv, const float* __restrict__ Wo,
                    float* __restrict__ out) {
  __shared__ __align__(16) u16 As[64 * 32];
  __shared__ __align__(16) u16 Bs[256 * 32];
  __shared__ __align__(16) u16 Vs[64 * 264];

  const int tid = threadIdx.x;
  const int w  = tid >> 6, l = tid & 63;
  const int q  = l >> 4, mr = l & 15;
  const int wm = w & 1, wn = w >> 1;
  const int row0 = blockIdx.x * 64;
  const int xr = tid >> 3, xg = (tid & 7) * 4;
  const int wr = tid >> 1, wh = (tid & 1) * 16;

  float4v acc[2][4];
#pragma unroll
  for (int i = 0; i < 2; ++i)
#pragma unroll
    for (int j = 0; j < 4; ++j) acc[i][j] = (float4v){0.f, 0.f, 0.f, 0.f};

  for (int kt = 0; kt < 24; ++kt) {
    const int k0 = kt * 32;
    {
      float4v v = *(const float4v*)(x + (size_t)(row0 + xr) * 768 + k0 + xg);
      union { u16 h[4]; uint2 u; } p;
      p.h[0] = f32_to_bf16(v[0]); p.h[1] = f32_to_bf16(v[1]);
      p.h[2] = f32_to_bf16(v[2]); p.h[3] = f32_to_bf16(v[3]);
      *(uint2*)(As + xr * 32 + xg) = p.u;
    }
    {
      const float* g = Wv + (size_t)wr * 768 + k0 + wh;
      union { u16 h[16]; short8 s[2]; } p;
#pragma unroll
      for (int u = 0; u < 4; ++u) {
        float4v v = *(const float4v*)(g + u * 4);
        p.h[u * 4 + 0] = f32_to_bf16(v[0]); p.h[u * 4 + 1] = f32_to_bf16(v[1]);
        p.h[u * 4 + 2] = f32_to_bf16(v[2]); p.h[u * 4 + 3] = f32_to_bf16(v[3]);
      }
      *(short8*)(Bs + wr * 32 + wh) = p.s[0];
      *(short8*)(Bs + wr * 32 + wh + 8) = p.s[1];
    }
    __syncthreads();

    short8 a[2], b[4];
#pragma unroll
    for (int i = 0; i < 2; ++i)
      a[i] = *(const short8*)(As + (wm * 32 + i * 16 + mr) * 32 + q * 8);
#pragma unroll
    for (int j = 0; j < 4; ++j)
      b[j] = *(const short8*)(Bs + (wn * 64 + j * 16 + mr) * 32 + q * 8);
#pragma unroll
    for (int i = 0; i < 2; ++i)
#pragma unroll
      for (int j = 0; j < 4; ++j)
        acc[i][j] = __builtin_amdgcn_mfma_f32_16x16x32_bf16(a[i], b[j], acc[i][j], 0, 0, 0);
    __syncthreads();
  }

#pragma unroll
  for (int i = 0; i < 2; ++i)
#pragma unroll
    for (int j = 0; j < 4; ++j) {
      int row = wm * 32 + i * 16 + q * 4;
      int col = wn * 64 + j * 16 + mr;
#pragma unroll
      for (int r = 0; r < 4; ++r)
        Vs[(row + r) * 264 + col] = f32_to_bf16(acc[i][j][r]);
    }
  __syncthreads();

  for (int c = 0; c < 3; ++c) {
    float4v acc2[2][4];
#pragma unroll
    for (int i = 0; i < 2; ++i)
#pragma unroll
      for (int j = 0; j < 4; ++j) acc2[i][j] = (float4v){0.f, 0.f, 0.f, 0.f};

    for (int kt = 0; kt < 8; ++kt) {
      const int k0 = kt * 32;
      {
        const float* g = Wo + (size_t)(c * 256 + wr) * 256 + k0 + wh;
        union { u16 h[16]; short8 s[2]; } p;
#pragma unroll
        for (int u = 0; u < 4; ++u) {
          float4v v = *(const float4v*)(g + u * 4);
          p.h[u * 4 + 0] = f32_to_bf16(v[0]); p.h[u * 4 + 1] = f32_to_bf16(v[1]);
          p.h[u * 4 + 2] = f32_to_bf16(v[2]); p.h[u * 4 + 3] = f32_to_bf16(v[3]);
        }
        *(short8*)(Bs + wr * 32 + wh) = p.s[0];
        *(short8*)(Bs + wr * 32 + wh + 8) = p.s[1];
      }
      __syncthreads();

      short8 a[2], b[4];
#pragma unroll
      for (int i = 0; i < 2; ++i)
        a[i] = *(const short8*)(Vs + (wm * 32 + i * 16 + mr) * 264 + k0 + q * 8);
#pragma unroll
      for (int j = 0; j < 4; ++j)
        b[j] = *(const short8*)(Bs + (wn * 64 + j * 16 + mr) * 32 + q * 8);
#pragma unroll
      for (int i = 0; i < 2; ++i)
#pragma unroll
        for (int j = 0; j < 4; ++j)
          acc2[i][j] = __builtin_amdgcn_mfma_f32_16x16x32_bf16(a[i], b[j], acc2[i][j], 0, 0, 0);
      __syncthreads();
    }

#pragma unroll
    for (int i = 0; i < 2; ++i)
#pragma unroll
      for (int j = 0; j < 4; ++j) {
        int row = row0 + wm * 32 + i * 16 + q * 4;
        int col = c * 256 + wn * 64 + j * 16 + mr;
#pragma unroll
        for (int r = 0; r < 4; ++r)
          out[(size_t)(row + r) * 768 + col] = acc2[i][j][r];
      }
  }
}

extern "C" void kernel_launch(void* const* d_in, const int* in_sizes, int n_in,
                              void* d_out, int out_size, void* d_ws, size_t ws_size,
                              hipStream_t stream) {
  (void)in_sizes; (void)n_in; (void)out_size;
  const float* x  = (const float*)d_in[0];  // [16384, 768]
  const float* Wv = (const float*)d_in[3];  // [256, 768]
  const float* Wo = (const float*)d_in[4];  // [768, 256]
  float* out = (float*)d_out;

  if (ws_size >= (size_t)768 * 768 * 2) {   // 1.18 MB f16 combined weight
    u16* wt = (u16*)d_ws;
    prep_w<<<dim3(576), dim3(256), 0, stream>>>(Wv, Wo, wt);
    gemm_xw<<<dim3(512), dim3(512), 0, stream>>>(x, wt, out);
  } else {
    fused_fallback<<<dim3(256), dim3(512), 0, stream>>>(x, Wv, Wo, out);
  }
}

// Round 7
// 133.837 us; speedup vs baseline: 1.0909x; 1.0909x over previous
//
#include <hip/hip_runtime.h>

// LlamaAttention — Round 14: r12 structure + 3-deep B prefetch pipeline.
//
// out = x @ (Wo @ Wv)^T  (softmax == I, established r0-r13).
// r13 post-mortem: halving stripes doubled required B rate -> slower (51.8);
// r12 (42.4) is B-LATENCY-bound in the K-loop: 1-deep dbuf leaves ~150+ cyc
// L2 latency exposed per tile. r14 = r12 config (64 rows, 256 blocks = 1/CU,
// W read once/block) with (1) 3-deep named B reg sets b0/b1/b2 (rule #20):
// ~240 cyc of MFMA between issue and consume covers L2 latency; (2) first
// 3 B-tiles issued BEFORE the x-stage (wt-only -> no barrier dep) so the
// L2 B-prologue overlaps the HBM stage burst. VGPR ~235 @ 2 waves/SIMD.

typedef unsigned short u16;
typedef __attribute__((ext_vector_type(8))) short short8;      // 16 B
typedef __attribute__((ext_vector_type(8))) _Float16 f16x8;    // 4 VGPR MFMA frag
typedef __attribute__((ext_vector_type(4))) float float4v;

__device__ inline u16 f16b(float f) {
  union { _Float16 h; u16 u; } v; v.h = (_Float16)f; return v.u;  // v_cvt_f16_f32 RNE
}

__device__ inline u16 f32_to_bf16(float f) {        // fallback path only
  union { float f; unsigned int u; } v; v.f = f;
  unsigned int r = v.u + 0x7FFF + ((v.u >> 16) & 1);
  return (u16)(r >> 16);
}

// ---------------- prep: W = Wo @ Wv, fp32 accum, f16 tiled ----------------
// wt layout: element (o, h) at wt[(h>>5)*24576 + o*32 + ((h>>3)&3)*8 + (h&7)]
// (wave frag load = 1 KB contiguous). Bit-identical W vs r10-r13.
__global__ __launch_bounds__(256)
void prep_w(const float* __restrict__ Wv, const float* __restrict__ Wo,
            u16* __restrict__ wt) {
  __shared__ __align__(16) float wo[4][256];            // 4 KB
  const int og = blockIdx.x / 3, hc = blockIdx.x % 3;   // 192 o-grp x 3 h-chunk
  const int o0 = og * 4;
  ((float4v*)&wo[0][0])[threadIdx.x] =
      ((const float4v*)(Wo + (size_t)o0 * 256))[threadIdx.x];
  __syncthreads();
  const int h = hc * 256 + threadIdx.x;
  float acc[4] = {0.f, 0.f, 0.f, 0.f};
  float wvA[8], wvB[8];
#pragma unroll
  for (int u = 0; u < 8; ++u) wvA[u] = Wv[(size_t)u * 768 + h];

#define PFMA(wv_, kk_)                                                       \
  _Pragma("unroll")                                                          \
  for (int j = 0; j < 4; ++j) {                                              \
    float4v c0 = *(const float4v*)(&wo[j][kk_]);                             \
    float4v c1 = *(const float4v*)(&wo[j][(kk_) + 4]);                       \
    acc[j] = fmaf(c0[0], wv_[0], acc[j]);                                    \
    acc[j] = fmaf(c0[1], wv_[1], acc[j]);                                    \
    acc[j] = fmaf(c0[2], wv_[2], acc[j]);                                    \
    acc[j] = fmaf(c0[3], wv_[3], acc[j]);                                    \
    acc[j] = fmaf(c1[0], wv_[4], acc[j]);                                    \
    acc[j] = fmaf(c1[1], wv_[5], acc[j]);                                    \
    acc[j] = fmaf(c1[2], wv_[6], acc[j]);                                    \
    acc[j] = fmaf(c1[3], wv_[7], acc[j]);                                    \
  }

  for (int k = 0; k < 240; k += 16) {
#pragma unroll
    for (int u = 0; u < 8; ++u) wvB[u] = Wv[(size_t)(k + 8 + u) * 768 + h];
    PFMA(wvA, k)
#pragma unroll
    for (int u = 0; u < 8; ++u) wvA[u] = Wv[(size_t)(k + 16 + u) * 768 + h];
    PFMA(wvB, k + 8)
  }
#pragma unroll
  for (int u = 0; u < 8; ++u) wvB[u] = Wv[(size_t)(248 + u) * 768 + h];
  PFMA(wvA, 240)
  PFMA(wvB, 248)
#undef PFMA

  const int kt = h >> 5, qq = (h >> 3) & 3, e = h & 7;
#pragma unroll
  for (int j = 0; j < 4; ++j)
    wt[(size_t)kt * 24576 + (o0 + j) * 32 + qq * 8 + e] = f16b(acc[j]);
}

// ---------------- main: out[16384,768] = x @ W^T, zero-barrier loop -------
// Block: 512 thr / 8 waves; 64 rows x 768 cols; wave w owns cols w*96..+95
// (disjoint -> W read once per block). LDS: x stripe f16 [64][96 chunks],
// chunk stored at c^(row&7) (A-frag reads 2-way max = free).
__global__ __launch_bounds__(512, 2)
void gemm_xw(const float* __restrict__ x, const u16* __restrict__ wt,
             float* __restrict__ out) {
  __shared__ __align__(16) u16 S[64 * 768];       // 96 KB -> 1 block/CU

  const int tid = threadIdx.x;
  const int w = tid >> 6, l = tid & 63;
  const int q = l >> 4, mr = l & 15;
  const int row0 = blockIdx.x * 64;

  // B-frag lane base: wt + col*32 + q*8, col = w*96 + jn*16 + mr
  const u16* wl = wt + (w * 96 + mr) * 32 + q * 8;
  const int akey = mr & 7;

  f16x8 a0[4], a1[4], a2[4], b0[6], b1[6], b2[6];

#define LDA(av_, kt_)                                                        \
  _Pragma("unroll")                                                          \
  for (int im = 0; im < 4; ++im)                                             \
    av_[im] = *(const f16x8*)(                                               \
        &S[(im * 16 + mr) * 768 + ((((kt_) * 4 + q) ^ akey) << 3)]);

#define LDB(bv_, kt_)                                                        \
  { const u16* gp = wl + (size_t)(kt_) * 24576;                              \
    _Pragma("unroll")                                                        \
    for (int jn = 0; jn < 6; ++jn)                                           \
      bv_[jn] = *(const f16x8*)(gp + jn * 512); }

  // ---- B prologue FIRST (no LDS dep): overlaps the x-stage HBM burst ----
  LDB(b0, 0)
  LDB(b1, 1)
  LDB(b2, 2)

  // ---- stage x[64][768] fp32 -> LDS f16, chunk-swizzled, ONCE ----
  {
    const int sr = ((w & 3) << 4) + mr;           // row 0..63
    const int half = w >> 2;                      // even/odd chunk quads
    const float* gr = x + (size_t)(row0 + sr) * 768;
    u16* lr = S + sr * 768;
    const int key = sr & 7;
#pragma unroll
    for (int j = 0; j < 12; ++j) {
      const int c = q + 4 * (2 * j + half);       // chunk 0..95
      float4v v0 = *(const float4v*)(gr + c * 8);
      float4v v1 = *(const float4v*)(gr + c * 8 + 4);
      union { u16 h[8]; short8 s; } p;
#pragma unroll
      for (int e = 0; e < 4; ++e) { p.h[e] = f16b(v0[e]); p.h[e + 4] = f16b(v1[e]); }
      *(short8*)(lr + ((c ^ key) << 3)) = p.s;
    }
  }
  __syncthreads();                                // the ONLY barrier

  float4v acc[4][6];
#pragma unroll
  for (int i = 0; i < 4; ++i)
#pragma unroll
    for (int j = 0; j < 6; ++j) acc[i][j] = (float4v){0.f, 0.f, 0.f, 0.f};

#define MM(av_, bv_)                                                         \
  { __builtin_amdgcn_s_setprio(1);                                           \
    _Pragma("unroll")                                                        \
    for (int im = 0; im < 4; ++im)                                           \
      _Pragma("unroll")                                                      \
      for (int jn = 0; jn < 6; ++jn)                                         \
        acc[im][jn] = __builtin_amdgcn_mfma_f32_16x16x32_f16(                \
            av_[im], bv_[jn], acc[im][jn], 0, 0, 0);                         \
    __builtin_amdgcn_s_setprio(0); }

  LDA(a0, 0)
  LDA(a1, 1)
  LDA(a2, 2)

  // Steady: unroll-3 slot rotation; each slot refilled 3 tiles ahead, so
  // ~2 MM windows (~240 cyc MFMA) sit between B issue and consume.
  for (int t = 0; t < 24; t += 3) {
    const bool pre = (t < 21);
    MM(a0, b0)
    if (pre) { LDB(b0, t + 3) LDA(a0, t + 3) }
    MM(a1, b1)
    if (pre) { LDB(b1, t + 4) LDA(a1, t + 4) }
    MM(a2, b2)
    if (pre) { LDB(b2, t + 5) LDA(a2, t + 5) }
  }

#undef LDA
#undef LDB
#undef MM

  // ---- epilogue: C/D col=lane&15, row=q*4+reg (m89-verified) ----
#pragma unroll
  for (int im = 0; im < 4; ++im)
#pragma unroll
    for (int jn = 0; jn < 6; ++jn) {
      const int r0 = row0 + im * 16 + q * 4;
      const int c  = w * 96 + jn * 16 + mr;
#pragma unroll
      for (int r = 0; r < 4; ++r)
        out[(size_t)(r0 + r) * 768 + c] = acc[im][jn][r];
    }
}

// ---------------- fallback (no workspace): verified r7 kernel ----------------
__global__ __launch_bounds__(512, 1)
void fused_fallback(const float* __restrict__ x,
                    const float* __restrict__ Wv, const float* __restrict__ Wo,
                    float* __restrict__ out) {
  __shared__ __align__(16) u16 As[64 * 32];
  __shared__ __align__(16) u16 Bs[256 * 32];
  __shared__ __align__(16) u16 Vs[64 * 264];

  const int tid = threadIdx.x;
  const int w  = tid >> 6, l = tid & 63;
  const int q  = l >> 4, mr = l & 15;
  const int wm = w & 1, wn = w >> 1;
  const int row0 = blockIdx.x * 64;
  const int xr = tid >> 3, xg = (tid & 7) * 4;
  const int wr = tid >> 1, wh = (tid & 1) * 16;

  float4v acc[2][4];
#pragma unroll
  for (int i = 0; i < 2; ++i)
#pragma unroll
    for (int j = 0; j < 4; ++j) acc[i][j] = (float4v){0.f, 0.f, 0.f, 0.f};

  for (int kt = 0; kt < 24; ++kt) {
    const int k0 = kt * 32;
    {
      float4v v = *(const float4v*)(x + (size_t)(row0 + xr) * 768 + k0 + xg);
      union { u16 h[4]; uint2 u; } p;
      p.h[0] = f32_to_bf16(v[0]); p.h[1] = f32_to_bf16(v[1]);
      p.h[2] = f32_to_bf16(v[2]); p.h[3] = f32_to_bf16(v[3]);
      *(uint2*)(As + xr * 32 + xg) = p.u;
    }
    {
      const float* g = Wv + (size_t)wr * 768 + k0 + wh;
      union { u16 h[16]; short8 s[2]; } p;
#pragma unroll
      for (int u = 0; u < 4; ++u) {
        float4v v = *(const float4v*)(g + u * 4);
        p.h[u * 4 + 0] = f32_to_bf16(v[0]); p.h[u * 4 + 1] = f32_to_bf16(v[1]);
        p.h[u * 4 + 2] = f32_to_bf16(v[2]); p.h[u * 4 + 3] = f32_to_bf16(v[3]);
      }
      *(short8*)(Bs + wr * 32 + wh) = p.s[0];
      *(short8*)(Bs + wr * 32 + wh + 8) = p.s[1];
    }
    __syncthreads();

    short8 a[2], b[4];
#pragma unroll
    for (int i = 0; i < 2; ++i)
      a[i] = *(const short8*)(As + (wm * 32 + i * 16 + mr) * 32 + q * 8);
#pragma unroll
    for (int j = 0; j < 4; ++j)
      b[j] = *(const short8*)(Bs + (wn * 64 + j * 16 + mr) * 32 + q * 8);
#pragma unroll
    for (int i = 0; i < 2; ++i)
#pragma unroll
      for (int j = 0; j < 4; ++j)
        acc[i][j] = __builtin_amdgcn_mfma_f32_16x16x32_bf16(a[i], b[j], acc[i][j], 0, 0, 0);
    __syncthreads();
  }

#pragma unroll
  for (int i = 0; i < 2; ++i)
#pragma unroll
    for (int j = 0; j < 4; ++j) {
      int row = wm * 32 + i * 16 + q * 4;
      int col = wn * 64 + j * 16 + mr;
#pragma unroll
      for (int r = 0; r < 4; ++r)
        Vs[(row + r) * 264 + col] = f32_to_bf16(acc[i][j][r]);
    }
  __syncthreads();

  for (int c = 0; c < 3; ++c) {
    float4v acc2[2][4];
#pragma unroll
    for (int i = 0; i < 2; ++i)
#pragma unroll
      for (int j = 0; j < 4; ++j) acc2[i][j] = (float4v){0.f, 0.f, 0.f, 0.f};

    for (int kt = 0; kt < 8; ++kt) {
      const int k0 = kt * 32;
      {
        const float* g = Wo + (size_t)(c * 256 + wr) * 256 + k0 + wh;
        union { u16 h[16]; short8 s[2]; } p;
#pragma unroll
        for (int u = 0; u < 4; ++u) {
          float4v v = *(const float4v*)(g + u * 4);
          p.h[u * 4 + 0] = f32_to_bf16(v[0]); p.h[u * 4 + 1] = f32_to_bf16(v[1]);
          p.h[u * 4 + 2] = f32_to_bf16(v[2]); p.h[u * 4 + 3] = f32_to_bf16(v[3]);
        }
        *(short8*)(Bs + wr * 32 + wh) = p.s[0];
        *(short8*)(Bs + wr * 32 + wh + 8) = p.s[1];
      }
      __syncthreads();

      short8 a[2], b[4];
#pragma unroll
      for (int i = 0; i < 2; ++i)
        a[i] = *(const short8*)(Vs + (wm * 32 + i * 16 + mr) * 264 + k0 + q * 8);
#pragma unroll
      for (int j = 0; j < 4; ++j)
        b[j] = *(const short8*)(Bs + (wn * 64 + j * 16 + mr) * 32 + q * 8);
#pragma unroll
      for (int i = 0; i < 2; ++i)
#pragma unroll
        for (int j = 0; j < 4; ++j)
          acc2[i][j] = __builtin_amdgcn_mfma_f32_16x16x32_bf16(a[i], b[j], acc2[i][j], 0, 0, 0);
      __syncthreads();
    }

#pragma unroll
    for (int i = 0; i < 2; ++i)
#pragma unroll
      for (int j = 0; j < 4; ++j) {
        int row = row0 + wm * 32 + i * 16 + q * 4;
        int col = c * 256 + wn * 64 + j * 16 + mr;
#pragma unroll
        for (int r = 0; r < 4; ++r)
          out[(size_t)(row + r) * 768 + col] = acc2[i][j][r];
      }
  }
}

extern "C" void kernel_launch(void* const* d_in, const int* in_sizes, int n_in,
                              void* d_out, int out_size, void* d_ws, size_t ws_size,
                              hipStream_t stream) {
  (void)in_sizes; (void)n_in; (void)out_size;
  const float* x  = (const float*)d_in[0];  // [16384, 768]
  const float* Wv = (const float*)d_in[3];  // [256, 768]
  const float* Wo = (const float*)d_in[4];  // [768, 256]
  float* out = (float*)d_out;

  if (ws_size >= (size_t)768 * 768 * 2) {   // 1.18 MB f16 combined weight
    u16* wt = (u16*)d_ws;
    prep_w<<<dim3(576), dim3(256), 0, stream>>>(Wv, Wo, wt);
    gemm_xw<<<dim3(256), dim3(512), 0, stream>>>(x, wt, out);
  } else {
    fused_fallback<<<dim3(256), dim3(512), 0, stream>>>(x, Wv, Wo, out);
  }
}